// Round 9
// baseline (96.333 us; speedup 1.0000x reference)
//
#include <hip/hip_runtime.h>

typedef unsigned short ushort_t;
typedef __bf16 bf16_8 __attribute__((ext_vector_type(8)));
typedef float f32x4 __attribute__((ext_vector_type(4)));

#define VOCAB 4101
#define KPAD  4160   // 65 * 64
#define NROWS 3072   // 1024 * 3
#define HDIM  768
#define ODIM  256

// ---- helpers -------------------------------------------------------------

static __device__ __forceinline__ unsigned short f2bf(float f) {
  unsigned int u = __float_as_uint(f);
  unsigned int r = (u + 0x7fffu + ((u >> 16) & 1u)) >> 16;
  return (unsigned short)r;
}

static __device__ __forceinline__ void async_copy16(const void* g, void* l) {
  __builtin_amdgcn_global_load_lds(
      (const __attribute__((address_space(1))) void*)g,
      (__attribute__((address_space(3))) void*)l, 16, 0, 0);
}

// ---- kernel 1: per-row histogram -> bf16 integer counts + scale ----------

__global__ __launch_bounds__(256)
void hist_kernel(const int* __restrict__ X, ushort_t* __restrict__ A,
                 float* __restrict__ scales) {
  const int r = blockIdx.x;
  __shared__ unsigned int h[KPAD];
  for (int i = threadIdx.x; i < KPAD; i += 256) h[i] = 0u;
  __syncthreads();

  const int4* xp = reinterpret_cast<const int4*>(X + (size_t)r * 4096);
  #pragma unroll
  for (int i = 0; i < 4; ++i) {
    int4 v = xp[i * 256 + threadIdx.x];
    atomicAdd(&h[v.x], 1u);
    atomicAdd(&h[v.y], 1u);
    atomicAdd(&h[v.z], 1u);
    atomicAdd(&h[v.w], 1u);
  }
  __syncthreads();

  const unsigned int ignored = h[0] + h[1] + h[2] + h[3] + h[4];
  const float s = 10.0f / (float)(4096u - ignored);
  if (threadIdx.x == 0) scales[r] = s;

  unsigned int* Ar = (unsigned int*)(A + (size_t)r * KPAD);
  for (int i = threadIdx.x; i < KPAD / 2; i += 256) {
    int i0 = 2 * i, i1 = 2 * i + 1;
    unsigned int c0 = (i0 >= 5 && i0 < VOCAB) ? h[i0] : 0u;
    unsigned int c1 = (i1 >= 5 && i1 < VOCAB) ? h[i1] : 0u;
    Ar[i] = (unsigned int)f2bf((float)c0) | ((unsigned int)f2bf((float)c1) << 16);
  }
}

// ---- kernel 2: transpose + fp32->bf16 convert: src[K][N] -> dst[N][Kpad] -

__global__ __launch_bounds__(256)
void transpose_convert(const float* __restrict__ src, ushort_t* __restrict__ dst,
                       int K, int N, int Kpad) {
  __shared__ ushort_t tile[64][65];
  const int kb = blockIdx.x * 64;
  const int nb = blockIdx.y * 64;
  const int tr = threadIdx.x >> 6;
  const int tc = threadIdx.x & 63;
  #pragma unroll
  for (int i = 0; i < 16; ++i) {
    int r = i * 4 + tr;
    int k = kb + r;
    float v = (k < K) ? src[(size_t)k * N + nb + tc] : 0.0f;
    tile[r][tc] = f2bf(v);
  }
  __syncthreads();
  #pragma unroll
  for (int i = 0; i < 16; ++i) {
    int r = i * 4 + tr;
    dst[(size_t)(nb + r) * Kpad + kb + tc] = tile[tc][r];
  }
}

// ---- GEMM1: BM=BN=96, BK=64, grid 32x8 = 256 blocks (exactly 1/CU) -------
// C[M][N] = A[M][K] * Bt[N][K]^T, fused scale+bias+relu -> bf16 H.
// 384 thr = 6 waves (2m x 3n); wave-tile 48x32 = acc[3][2] of 16x16.
// T2 XOR swizzle (linear gload_lds dest, inverse-swizzled global src, same
// XOR on ds_read).  T3+T4 3-deep pipeline: 3 LDS buffers; 4 gloads/thread
// per STAGE (2 A + 2 B, uniform); per tile: s_waitcnt vmcnt(4) [tile t
// landed, t+1 in flight] -> s_barrier -> STAGE(t+2) -> ds_read+MFMA.
// Buffer safety: STAGE(t+2) writes the buffer last read at t-1; the barrier
// at tile t follows compute(t-1) in program order for every wave.

__global__ __launch_bounds__(384)
void gemm1_fused(const ushort_t* __restrict__ A, int lda,
                 const ushort_t* __restrict__ Bt, int ldb,
                 int ktiles,
                 const float* __restrict__ scales,
                 const float* __restrict__ bias,
                 ushort_t* __restrict__ H) {
  __shared__ __align__(16) ushort_t Alds[3][96 * 64];   // 3 x 12 KB
  __shared__ __align__(16) ushort_t Blds[3][96 * 64];   // 3 x 12 KB
  const int tid  = threadIdx.x;
  const int lane = tid & 63;
  const int wv   = tid >> 6;      // 0..5
  const int wrow = wv / 3;        // 0..1  -> 48 rows each
  const int wcol = wv % 3;        // 0..2  -> 32 cols each
  const int m0   = blockIdx.x * 96;
  const int n0   = blockIdx.y * 96;

  f32x4 acc[3][2];
  #pragma unroll
  for (int m = 0; m < 3; ++m)
    #pragma unroll
    for (int n = 0; n < 2; ++n)
      acc[m][n] = (f32x4){0.f, 0.f, 0.f, 0.f};

  // A tile: 96 rows x 8 chunks = 768 chunks; 384 thr -> 2 each. Same for B.
#define STAGE(bi, kt)                                                          \
  {                                                                            \
    const int k0_ = (kt) * 64;                                                 \
    _Pragma("unroll")                                                          \
    for (int i = 0; i < 2; ++i) {                                              \
      const int cd  = i * 384 + tid;                                           \
      const int row = cd >> 3;                                                 \
      const int cc  = (cd & 7) ^ (row & 7);                                    \
      async_copy16(A + (size_t)(m0 + row) * lda + k0_ + cc * 8,                \
                   (char*)&Alds[bi][0] + cd * 16);                             \
    }                                                                          \
    _Pragma("unroll")                                                          \
    for (int i = 0; i < 2; ++i) {                                              \
      const int cd  = i * 384 + tid;                                           \
      const int row = cd >> 3;                                                 \
      const int cc  = (cd & 7) ^ (row & 7);                                    \
      async_copy16(Bt + (size_t)(n0 + row) * ldb + k0_ + cc * 8,               \
                   (char*)&Blds[bi][0] + cd * 16);                             \
    }                                                                          \
  }

  STAGE(0, 0);
  STAGE(1, 1);

  int cur = 0;
  for (int t = 0; t < ktiles; ++t) {
    if (t + 1 < ktiles) {
      asm volatile("s_waitcnt vmcnt(4)" ::: "memory");   // tile t landed
    } else {
      asm volatile("s_waitcnt vmcnt(0)" ::: "memory");
    }
    __builtin_amdgcn_s_barrier();
    __builtin_amdgcn_sched_barrier(0);

    if (t + 2 < ktiles) {
      int nb = cur + 2; if (nb >= 3) nb -= 3;
      STAGE(nb, t + 2);                                  // issue-early
    }

    const int hi = lane >> 4;                  // 0..3
    #pragma unroll
    for (int kk = 0; kk < 2; ++kk) {
      bf16_8 af[3], bf[2];
      #pragma unroll
      for (int m = 0; m < 3; ++m) {
        const int ra = wrow * 48 + m * 16 + (lane & 15);
        const int ca = kk * 4 + hi;
        af[m] = *(const bf16_8*)((const char*)&Alds[cur][0] +
                                 (ra * 8 + (ca ^ (ra & 7))) * 16);
      }
      #pragma unroll
      for (int n = 0; n < 2; ++n) {
        const int rb = wcol * 32 + n * 16 + (lane & 15);
        const int cb = kk * 4 + hi;
        bf[n] = *(const bf16_8*)((const char*)&Blds[cur][0] +
                                 (rb * 8 + (cb ^ (rb & 7))) * 16);
      }
      #pragma unroll
      for (int m = 0; m < 3; ++m)
        #pragma unroll
        for (int n = 0; n < 2; ++n)
          acc[m][n] = __builtin_amdgcn_mfma_f32_16x16x32_bf16(af[m], bf[n],
                                                              acc[m][n], 0, 0, 0);
    }
    __builtin_amdgcn_sched_barrier(0);
    cur = (cur + 1 == 3) ? 0 : cur + 1;
  }
#undef STAGE

  // D col = lane&15, row = 4*(lane>>4)+reg
  const int rbase = (lane >> 4) * 4;
  const int cf    = lane & 15;
  #pragma unroll
  for (int m = 0; m < 3; ++m) {
    #pragma unroll
    for (int n = 0; n < 2; ++n) {
      #pragma unroll
      for (int reg = 0; reg < 4; ++reg) {
        const int gr = m0 + wrow * 48 + m * 16 + rbase + reg;
        const int gc = n0 + wcol * 32 + n * 16 + cf;
        float v = fmaxf(acc[m][n][reg] * scales[gr] + bias[gc], 0.0f);
        H[(size_t)gr * HDIM + gc] = f2bf(v);
      }
    }
  }
}

// ---- GEMM2: BM=96, BN=32, BK=64, grid 32x8 = 256 blocks (R8-proven) ------
// 384 thr = 6 waves (6m x 1n); wave-tile 16x32 = acc[1][2].
// out[(row%3)*262144 + (row/3)*256 + col] = acc + bias[col]

__global__ __launch_bounds__(384)
void gemm2_fused(const ushort_t* __restrict__ A, int lda,
                 const ushort_t* __restrict__ Bt, int ldb,
                 int ktiles,
                 const float* __restrict__ bias,
                 float* __restrict__ outp) {
  __shared__ __align__(16) ushort_t Alds[2][96 * 64];   // 2 x 12 KB
  __shared__ __align__(16) ushort_t Blds[2][32 * 64];   // 2 x  4 KB
  const int tid  = threadIdx.x;
  const int lane = tid & 63;
  const int wv   = tid >> 6;      // 0..5 -> 16 rows each
  const int m0   = blockIdx.x * 96;
  const int n0   = blockIdx.y * 32;

  f32x4 acc[2];
  acc[0] = (f32x4){0.f, 0.f, 0.f, 0.f};
  acc[1] = (f32x4){0.f, 0.f, 0.f, 0.f};

#define STAGE(bi, kt)                                                          \
  {                                                                            \
    const int k0_ = (kt) * 64;                                                 \
    _Pragma("unroll")                                                          \
    for (int i = 0; i < 2; ++i) {                                              \
      const int cd  = i * 384 + tid;                                           \
      const int row = cd >> 3;                                                 \
      const int cc  = (cd & 7) ^ (row & 7);                                    \
      async_copy16(A + (size_t)(m0 + row) * lda + k0_ + cc * 8,                \
                   (char*)&Alds[bi][0] + cd * 16);                             \
    }                                                                          \
    if (tid < 256) {                                                           \
      const int cd  = tid;                                                     \
      const int row = cd >> 3;                                                 \
      const int cc  = (cd & 7) ^ (row & 7);                                    \
      async_copy16(Bt + (size_t)(n0 + row) * ldb + k0_ + cc * 8,               \
                   (char*)&Blds[bi][0] + cd * 16);                             \
    }                                                                          \
  }

  STAGE(0, 0);
  __syncthreads();

  int cur = 0;
  for (int t = 0; t < ktiles; ++t) {
    if (t + 1 < ktiles) STAGE(cur ^ 1, t + 1);
    const int hi = lane >> 4;
    #pragma unroll
    for (int kk = 0; kk < 2; ++kk) {
      bf16_8 af, bf[2];
      {
        const int ra = wv * 16 + (lane & 15);
        const int ca = kk * 4 + hi;
        af = *(const bf16_8*)((const char*)&Alds[cur][0] +
                              (ra * 8 + (ca ^ (ra & 7))) * 16);
      }
      #pragma unroll
      for (int n = 0; n < 2; ++n) {
        const int rb = n * 16 + (lane & 15);
        const int cb = kk * 4 + hi;
        bf[n] = *(const bf16_8*)((const char*)&Blds[cur][0] +
                                 (rb * 8 + (cb ^ (rb & 7))) * 16);
      }
      #pragma unroll
      for (int n = 0; n < 2; ++n)
        acc[n] = __builtin_amdgcn_mfma_f32_16x16x32_bf16(af, bf[n], acc[n], 0, 0, 0);
    }
    __syncthreads();
    cur ^= 1;
  }
#undef STAGE

  const int rbase = (lane >> 4) * 4;
  const int cf    = lane & 15;
  #pragma unroll
  for (int n = 0; n < 2; ++n) {
    #pragma unroll
    for (int reg = 0; reg < 4; ++reg) {
      const int gr = m0 + wv * 16 + rbase + reg;
      const int gc = n0 + n * 16 + cf;
      float v = acc[n][reg] + bias[gc];
      outp[(size_t)(gr % 3) * (1024 * ODIM) + (size_t)(gr / 3) * ODIM + gc] = v;
    }
  }
}

// ---- launch --------------------------------------------------------------

extern "C" void kernel_launch(void* const* d_in, const int* in_sizes, int n_in,
                              void* d_out, int out_size, void* d_ws, size_t ws_size,
                              hipStream_t stream) {
  const int*   X  = (const int*)d_in[0];
  const float* W1 = (const float*)d_in[1];
  const float* b1 = (const float*)d_in[2];
  const float* W2 = (const float*)d_in[3];
  const float* b2 = (const float*)d_in[4];
  float* out = (float*)d_out;

  char* ws = (char*)d_ws;
  ushort_t* A      = (ushort_t*)(ws);                  // 25,559,040 B
  ushort_t* W1T    = (ushort_t*)(ws + 25559040);       //  6,389,760 B
  ushort_t* H      = (ushort_t*)(ws + 31948800);       //  4,718,592 B
  ushort_t* W2T    = (ushort_t*)(ws + 36667392);       //    393,216 B
  float*    scales = (float*)   (ws + 37060608);       //     12,288 B

  hist_kernel<<<NROWS, 256, 0, stream>>>(X, A, scales);
  transpose_convert<<<dim3(KPAD / 64, HDIM / 64), 256, 0, stream>>>(W1, W1T, VOCAB, HDIM, KPAD);
  transpose_convert<<<dim3(HDIM / 64, ODIM / 64), 256, 0, stream>>>(W2, W2T, HDIM, ODIM, HDIM);

  // GEMM1: M=3072 N=768 K=4160 (65 tiles); grid 32x8 = 256 blocks
  gemm1_fused<<<dim3(NROWS / 96, HDIM / 96), 384, 0, stream>>>(
      A, KPAD, W1T, KPAD, KPAD / 64, scales, b1, H);

  // GEMM2: M=3072 N=256 K=768 (12 tiles); grid 32x8 = 256 blocks
  gemm2_fused<<<dim3(NROWS / 96, ODIM / 32), 384, 0, stream>>>(
      H, HDIM, W2T, HDIM, HDIM / 64, b2, out);
}

// Round 10
// 72.009 us; speedup vs baseline: 1.3378x; 1.3378x over previous
//
#include <hip/hip_runtime.h>

typedef unsigned short ushort_t;
typedef __bf16 bf16_8 __attribute__((ext_vector_type(8)));
typedef float f32x4 __attribute__((ext_vector_type(4)));

#define VOCAB 4101
#define KPAD  4224   // 33 * 128
#define NROWS 3072   // 1024 * 3
#define HDIM  768
#define ODIM  256

// ---- helpers -------------------------------------------------------------

static __device__ __forceinline__ unsigned short f2bf(float f) {
  unsigned int u = __float_as_uint(f);
  unsigned int r = (u + 0x7fffu + ((u >> 16) & 1u)) >> 16;
  return (unsigned short)r;
}

static __device__ __forceinline__ void async_copy16(const void* g, void* l) {
  __builtin_amdgcn_global_load_lds(
      (const __attribute__((address_space(1))) void*)g,
      (__attribute__((address_space(3))) void*)l, 16, 0, 0);
}

// ---- kernel 1: per-row histogram -> bf16 integer counts + scale ----------

__global__ __launch_bounds__(256)
void hist_kernel(const int* __restrict__ X, ushort_t* __restrict__ A,
                 float* __restrict__ scales) {
  const int r = blockIdx.x;
  __shared__ unsigned int h[KPAD];
  for (int i = threadIdx.x; i < KPAD; i += 256) h[i] = 0u;
  __syncthreads();

  const int4* xp = reinterpret_cast<const int4*>(X + (size_t)r * 4096);
  #pragma unroll
  for (int i = 0; i < 4; ++i) {
    int4 v = xp[i * 256 + threadIdx.x];
    atomicAdd(&h[v.x], 1u);
    atomicAdd(&h[v.y], 1u);
    atomicAdd(&h[v.z], 1u);
    atomicAdd(&h[v.w], 1u);
  }
  __syncthreads();

  const unsigned int ignored = h[0] + h[1] + h[2] + h[3] + h[4];
  const float s = 10.0f / (float)(4096u - ignored);
  if (threadIdx.x == 0) scales[r] = s;

  unsigned int* Ar = (unsigned int*)(A + (size_t)r * KPAD);
  for (int i = threadIdx.x; i < KPAD / 2; i += 256) {
    int i0 = 2 * i, i1 = 2 * i + 1;
    unsigned int c0 = (i0 >= 5 && i0 < VOCAB) ? h[i0] : 0u;
    unsigned int c1 = (i1 >= 5 && i1 < VOCAB) ? h[i1] : 0u;
    Ar[i] = (unsigned int)f2bf((float)c0) | ((unsigned int)f2bf((float)c1) << 16);
  }
}

// ---- kernel 2: transpose + fp32->bf16 convert: src[K][N] -> dst[N][Kpad] -

__global__ __launch_bounds__(256)
void transpose_convert(const float* __restrict__ src, ushort_t* __restrict__ dst,
                       int K, int N, int Kpad) {
  __shared__ ushort_t tile[64][65];
  const int kb = blockIdx.x * 64;
  const int nb = blockIdx.y * 64;
  const int tr = threadIdx.x >> 6;
  const int tc = threadIdx.x & 63;
  #pragma unroll
  for (int i = 0; i < 16; ++i) {
    int r = i * 4 + tr;
    int k = kb + r;
    float v = (k < K) ? src[(size_t)k * N + nb + tc] : 0.0f;
    tile[r][tc] = f2bf(v);
  }
  __syncthreads();
  #pragma unroll
  for (int i = 0; i < 16; ++i) {
    int r = i * 4 + tr;
    dst[(size_t)(nb + r) * Kpad + kb + tc] = tile[tc][r];
  }
}

// ---- GEMM1: BM=BN=96, BK=128, grid 32x8 = 256 blocks (exactly 1/CU) ------
// C[M][N] = A[M][K] * Bt[N][K]^T, fused scale+bias+relu -> bf16 H.
// 384 thr = 6 waves (2m x 3n); wave-tile 48x32 = acc[3][2] of 16x16.
// R8-proven 2-phase dbuf (STAGE next at loop top, one __syncthreads/tile).
// T2 XOR swizzle, rule #21 both-sides: linear gload_lds dest, inverse-
// swizzled global src (chunk cc = c ^ (row&7); row = 256B = 16 chunks,
// XOR on low 3 chunk bits only), same XOR on ds_read.
// Per tile: 4 kk-steps x (5 ds_read_b128 + 6 MFMA) per wave; one barrier.

__global__ __launch_bounds__(384)
void gemm1_fused(const ushort_t* __restrict__ A, int lda,
                 const ushort_t* __restrict__ Bt, int ldb,
                 int ktiles,
                 const float* __restrict__ scales,
                 const float* __restrict__ bias,
                 ushort_t* __restrict__ H) {
  __shared__ __align__(16) ushort_t Alds[2][96 * 128];   // 2 x 24 KB
  __shared__ __align__(16) ushort_t Blds[2][96 * 128];   // 2 x 24 KB
  const int tid  = threadIdx.x;
  const int lane = tid & 63;
  const int wv   = tid >> 6;      // 0..5
  const int wrow = wv / 3;        // 0..1  -> 48 rows each
  const int wcol = wv % 3;        // 0..2  -> 32 cols each
  const int m0   = blockIdx.x * 96;
  const int n0   = blockIdx.y * 96;

  f32x4 acc[3][2];
  #pragma unroll
  for (int m = 0; m < 3; ++m)
    #pragma unroll
    for (int n = 0; n < 2; ++n)
      acc[m][n] = (f32x4){0.f, 0.f, 0.f, 0.f};

  // A tile: 96 rows x 16 chunks = 1536 chunks; 384 thr -> 4 each. Same B.
#define STAGE(bi, kt)                                                          \
  {                                                                            \
    const int k0_ = (kt) * 128;                                                \
    _Pragma("unroll")                                                          \
    for (int i = 0; i < 4; ++i) {                                              \
      const int cd  = i * 384 + tid;                                           \
      const int row = cd >> 4;                                                 \
      const int cc  = (cd & 15) ^ (row & 7);                                   \
      async_copy16(A + (size_t)(m0 + row) * lda + k0_ + cc * 8,                \
                   (char*)&Alds[bi][0] + cd * 16);                             \
    }                                                                          \
    _Pragma("unroll")                                                          \
    for (int i = 0; i < 4; ++i) {                                              \
      const int cd  = i * 384 + tid;                                           \
      const int row = cd >> 4;                                                 \
      const int cc  = (cd & 15) ^ (row & 7);                                   \
      async_copy16(Bt + (size_t)(n0 + row) * ldb + k0_ + cc * 8,               \
                   (char*)&Blds[bi][0] + cd * 16);                             \
    }                                                                          \
  }

  STAGE(0, 0);
  __syncthreads();

  int cur = 0;
  for (int t = 0; t < ktiles; ++t) {
    if (t + 1 < ktiles) STAGE(cur ^ 1, t + 1);
    const int hi = lane >> 4;                  // 0..3
    #pragma unroll
    for (int kk = 0; kk < 4; ++kk) {
      bf16_8 af[3], bf[2];
      #pragma unroll
      for (int m = 0; m < 3; ++m) {
        const int ra = wrow * 48 + m * 16 + (lane & 15);
        const int ca = kk * 4 + hi;            // chunk col 0..15
        af[m] = *(const bf16_8*)((const char*)&Alds[cur][0] +
                                 (ra * 16 + (ca ^ (ra & 7))) * 16);
      }
      #pragma unroll
      for (int n = 0; n < 2; ++n) {
        const int rb = wcol * 32 + n * 16 + (lane & 15);
        const int cb = kk * 4 + hi;
        bf[n] = *(const bf16_8*)((const char*)&Blds[cur][0] +
                                 (rb * 16 + (cb ^ (rb & 7))) * 16);
      }
      #pragma unroll
      for (int m = 0; m < 3; ++m)
        #pragma unroll
        for (int n = 0; n < 2; ++n)
          acc[m][n] = __builtin_amdgcn_mfma_f32_16x16x32_bf16(af[m], bf[n],
                                                              acc[m][n], 0, 0, 0);
    }
    __syncthreads();
    cur ^= 1;
  }
#undef STAGE

  // D col = lane&15, row = 4*(lane>>4)+reg
  const int rbase = (lane >> 4) * 4;
  const int cf    = lane & 15;
  #pragma unroll
  for (int m = 0; m < 3; ++m) {
    #pragma unroll
    for (int n = 0; n < 2; ++n) {
      #pragma unroll
      for (int reg = 0; reg < 4; ++reg) {
        const int gr = m0 + wrow * 48 + m * 16 + rbase + reg;
        const int gc = n0 + wcol * 32 + n * 16 + cf;
        float v = fmaxf(acc[m][n][reg] * scales[gr] + bias[gc], 0.0f);
        H[(size_t)gr * HDIM + gc] = f2bf(v);
      }
    }
  }
}

// ---- GEMM2: BM=96, BN=32, BK=128, grid 32x8 = 256 blocks -----------------
// 384 thr = 6 waves (6m x 1n); wave-tile 16x32 = acc[1][2]; 6 K-tiles.
// out[(row%3)*262144 + (row/3)*256 + col] = acc + bias[col]

__global__ __launch_bounds__(384)
void gemm2_fused(const ushort_t* __restrict__ A, int lda,
                 const ushort_t* __restrict__ Bt, int ldb,
                 int ktiles,
                 const float* __restrict__ bias,
                 float* __restrict__ outp) {
  __shared__ __align__(16) ushort_t Alds[2][96 * 128];   // 2 x 24 KB
  __shared__ __align__(16) ushort_t Blds[2][32 * 128];   // 2 x  8 KB
  const int tid  = threadIdx.x;
  const int lane = tid & 63;
  const int wv   = tid >> 6;      // 0..5 -> 16 rows each
  const int m0   = blockIdx.x * 96;
  const int n0   = blockIdx.y * 32;

  f32x4 acc[2];
  acc[0] = (f32x4){0.f, 0.f, 0.f, 0.f};
  acc[1] = (f32x4){0.f, 0.f, 0.f, 0.f};

  // A tile: 1536 chunks -> 4/thread; B tile: 512 chunks -> 1 + partial.
#define STAGE(bi, kt)                                                          \
  {                                                                            \
    const int k0_ = (kt) * 128;                                                \
    _Pragma("unroll")                                                          \
    for (int i = 0; i < 4; ++i) {                                              \
      const int cd  = i * 384 + tid;                                           \
      const int row = cd >> 4;                                                 \
      const int cc  = (cd & 15) ^ (row & 7);                                   \
      async_copy16(A + (size_t)(m0 + row) * lda + k0_ + cc * 8,                \
                   (char*)&Alds[bi][0] + cd * 16);                             \
    }                                                                          \
    {                                                                          \
      const int cd  = tid;                                                     \
      const int row = cd >> 4;                                                 \
      const int cc  = (cd & 15) ^ (row & 7);                                   \
      async_copy16(Bt + (size_t)(n0 + row) * ldb + k0_ + cc * 8,               \
                   (char*)&Blds[bi][0] + cd * 16);                             \
    }                                                                          \
    if (tid < 128) {                                                           \
      const int cd  = 384 + tid;                                               \
      const int row = cd >> 4;                                                 \
      const int cc  = (cd & 15) ^ (row & 7);                                   \
      async_copy16(Bt + (size_t)(n0 + row) * ldb + k0_ + cc * 8,               \
                   (char*)&Blds[bi][0] + cd * 16);                             \
    }                                                                          \
  }

  STAGE(0, 0);
  __syncthreads();

  int cur = 0;
  for (int t = 0; t < ktiles; ++t) {
    if (t + 1 < ktiles) STAGE(cur ^ 1, t + 1);
    const int hi = lane >> 4;
    #pragma unroll
    for (int kk = 0; kk < 4; ++kk) {
      bf16_8 af, bf[2];
      {
        const int ra = wv * 16 + (lane & 15);
        const int ca = kk * 4 + hi;
        af = *(const bf16_8*)((const char*)&Alds[cur][0] +
                              (ra * 16 + (ca ^ (ra & 7))) * 16);
      }
      #pragma unroll
      for (int n = 0; n < 2; ++n) {
        const int rb = n * 16 + (lane & 15);
        const int cb = kk * 4 + hi;
        bf[n] = *(const bf16_8*)((const char*)&Blds[cur][0] +
                                 (rb * 16 + (cb ^ (rb & 7))) * 16);
      }
      #pragma unroll
      for (int n = 0; n < 2; ++n)
        acc[n] = __builtin_amdgcn_mfma_f32_16x16x32_bf16(af, bf[n], acc[n], 0, 0, 0);
    }
    __syncthreads();
    cur ^= 1;
  }
#undef STAGE

  const int rbase = (lane >> 4) * 4;
  const int cf    = lane & 15;
  #pragma unroll
  for (int n = 0; n < 2; ++n) {
    #pragma unroll
    for (int reg = 0; reg < 4; ++reg) {
      const int gr = m0 + wv * 16 + rbase + reg;
      const int gc = n0 + n * 16 + cf;
      float v = acc[n][reg] + bias[gc];
      outp[(size_t)(gr % 3) * (1024 * ODIM) + (size_t)(gr / 3) * ODIM + gc] = v;
    }
  }
}

// ---- launch --------------------------------------------------------------

extern "C" void kernel_launch(void* const* d_in, const int* in_sizes, int n_in,
                              void* d_out, int out_size, void* d_ws, size_t ws_size,
                              hipStream_t stream) {
  const int*   X  = (const int*)d_in[0];
  const float* W1 = (const float*)d_in[1];
  const float* b1 = (const float*)d_in[2];
  const float* W2 = (const float*)d_in[3];
  const float* b2 = (const float*)d_in[4];
  float* out = (float*)d_out;

  char* ws = (char*)d_ws;
  ushort_t* A      = (ushort_t*)(ws);                  // 3072*4224*2 = 25,952,256 B
  ushort_t* W1T    = (ushort_t*)(ws + 25952256);       //  768*4224*2 =  6,488,064 B
  ushort_t* H      = (ushort_t*)(ws + 32440320);       // 3072*768*2  =  4,718,592 B
  ushort_t* W2T    = (ushort_t*)(ws + 37158912);       //  256*768*2  =    393,216 B
  float*    scales = (float*)   (ws + 37552128);       //     12,288 B

  hist_kernel<<<NROWS, 256, 0, stream>>>(X, A, scales);
  transpose_convert<<<dim3(KPAD / 64, HDIM / 64), 256, 0, stream>>>(W1, W1T, VOCAB, HDIM, KPAD);
  transpose_convert<<<dim3(HDIM / 64, ODIM / 64), 256, 0, stream>>>(W2, W2T, HDIM, ODIM, HDIM);

  // GEMM1: M=3072 N=768 K=4224 (33 tiles of 128); grid 32x8 = 256 blocks
  gemm1_fused<<<dim3(NROWS / 96, HDIM / 96), 384, 0, stream>>>(
      A, KPAD, W1T, KPAD, KPAD / 128, scales, b1, H);

  // GEMM2: M=3072 N=256 K=768 (6 tiles of 128); grid 32x8 = 256 blocks
  gemm2_fused<<<dim3(NROWS / 96, ODIM / 32), 384, 0, stream>>>(
      H, HDIM, W2T, HDIM, HDIM / 128, b2, out);
}

// Round 11
// 63.188 us; speedup vs baseline: 1.5245x; 1.1396x over previous
//
#include <hip/hip_runtime.h>

typedef unsigned short ushort_t;
typedef __bf16 bf16_8 __attribute__((ext_vector_type(8)));
typedef float f32x4 __attribute__((ext_vector_type(4)));

#define VOCAB 4101
#define KPAD  4224   // 33 * 128 = 66 * 64
#define NROWS 3072   // 1024 * 3
#define HDIM  768
#define ODIM  256

// ---- helpers -------------------------------------------------------------

static __device__ __forceinline__ unsigned short f2bf(float f) {
  unsigned int u = __float_as_uint(f);
  unsigned int r = (u + 0x7fffu + ((u >> 16) & 1u)) >> 16;
  return (unsigned short)r;
}

static __device__ __forceinline__ void async_copy16(const void* g, void* l) {
  __builtin_amdgcn_global_load_lds(
      (const __attribute__((address_space(1))) void*)g,
      (__attribute__((address_space(3))) void*)l, 16, 0, 0);
}

// ---- fused prep kernel: histogram + both weight transposes ---------------
// Block roles by flat blockIdx.x:
//   [0, 3072)           : per-row histogram -> bf16 counts A + scales
//   [3072, 3072+792)    : W1 [4101][768] -> W1T [768][4224] bf16 (66x12 tiles)
//   [3864, 3864+48)     : W2 [768][256]  -> W2T [256][768]  bf16 (12x4 tiles)
// LDS union: hist h[4224] uint (16896 B) vs tp tile[64][65] ushort (8320 B).

__global__ __launch_bounds__(256)
void prep_kernel(const int* __restrict__ X,
                 const float* __restrict__ W1,
                 const float* __restrict__ W2,
                 ushort_t* __restrict__ A,
                 ushort_t* __restrict__ W1T,
                 ushort_t* __restrict__ W2T,
                 float* __restrict__ scales) {
  __shared__ __align__(16) unsigned char smem[16896];
  const int bid = blockIdx.x;

  if (bid < NROWS) {
    // ---------------- histogram role ----------------
    unsigned int* h = (unsigned int*)smem;
    const int r = bid;
    for (int i = threadIdx.x; i < KPAD; i += 256) h[i] = 0u;
    __syncthreads();

    const int4* xp = reinterpret_cast<const int4*>(X + (size_t)r * 4096);
    #pragma unroll
    for (int i = 0; i < 4; ++i) {
      int4 v = xp[i * 256 + threadIdx.x];
      atomicAdd(&h[v.x], 1u);
      atomicAdd(&h[v.y], 1u);
      atomicAdd(&h[v.z], 1u);
      atomicAdd(&h[v.w], 1u);
    }
    __syncthreads();

    const unsigned int ignored = h[0] + h[1] + h[2] + h[3] + h[4];
    const float s = 10.0f / (float)(4096u - ignored);
    if (threadIdx.x == 0) scales[r] = s;

    unsigned int* Ar = (unsigned int*)(A + (size_t)r * KPAD);
    for (int i = threadIdx.x; i < KPAD / 2; i += 256) {
      int i0 = 2 * i, i1 = 2 * i + 1;
      unsigned int c0 = (i0 >= 5 && i0 < VOCAB) ? h[i0] : 0u;
      unsigned int c1 = (i1 >= 5 && i1 < VOCAB) ? h[i1] : 0u;
      Ar[i] = (unsigned int)f2bf((float)c0) | ((unsigned int)f2bf((float)c1) << 16);
    }
  } else {
    // ---------------- transpose roles ----------------
    ushort_t (*tile)[65] = (ushort_t(*)[65])smem;
    const float* src; ushort_t* dst;
    int K, N, Kpad, kb, nb;
    if (bid < NROWS + 792) {
      const int t = bid - NROWS;           // tp1: 66 x 12 tiles
      src = W1; dst = W1T; K = VOCAB; N = HDIM; Kpad = KPAD;
      kb = (t % 66) * 64; nb = (t / 66) * 64;
    } else {
      const int t = bid - NROWS - 792;     // tp2: 12 x 4 tiles
      src = W2; dst = W2T; K = HDIM; N = ODIM; Kpad = HDIM;
      kb = (t % 12) * 64; nb = (t / 12) * 64;
    }
    const int tr = threadIdx.x >> 6;
    const int tc = threadIdx.x & 63;
    #pragma unroll
    for (int i = 0; i < 16; ++i) {
      int r = i * 4 + tr;
      int k = kb + r;
      float v = (k < K) ? src[(size_t)k * N + nb + tc] : 0.0f;
      tile[r][tc] = f2bf(v);
    }
    __syncthreads();
    #pragma unroll
    for (int i = 0; i < 16; ++i) {
      int r = i * 4 + tr;
      dst[(size_t)(nb + r) * Kpad + kb + tc] = tile[tc][r];
    }
  }
}

// ---- GEMM1: BM=BN=96, BK=128, grid 32x8 = 256 blocks (exactly 1/CU) ------
// C[M][N] = A[M][K] * Bt[N][K]^T, fused scale+bias+relu -> bf16 H.
// 256 thr = 4 waves (2m x 2n); wave-tile 48x48 = acc[3][3] of 16x16.
// Read-amplification: BK*(96*2 + 96*2) -> 96 b128/tile (was 120 at 2x3).
// R8-proven 2-phase dbuf; T2 XOR swizzle (linear gload_lds dest, inverse-
// swizzled global src chunk cc = c ^ (row&7), same XOR on ds_read).

__global__ __launch_bounds__(256)
void gemm1_fused(const ushort_t* __restrict__ A, int lda,
                 const ushort_t* __restrict__ Bt, int ldb,
                 int ktiles,
                 const float* __restrict__ scales,
                 const float* __restrict__ bias,
                 ushort_t* __restrict__ H) {
  __shared__ __align__(16) ushort_t Alds[2][96 * 128];   // 2 x 24 KB
  __shared__ __align__(16) ushort_t Blds[2][96 * 128];   // 2 x 24 KB
  const int tid  = threadIdx.x;
  const int lane = tid & 63;
  const int wv   = tid >> 6;      // 0..3
  const int wrow = wv >> 1;       // 0..1  -> 48 rows each
  const int wcol = wv & 1;        // 0..1  -> 48 cols each
  const int m0   = blockIdx.x * 96;
  const int n0   = blockIdx.y * 96;

  f32x4 acc[3][3];
  #pragma unroll
  for (int m = 0; m < 3; ++m)
    #pragma unroll
    for (int n = 0; n < 3; ++n)
      acc[m][n] = (f32x4){0.f, 0.f, 0.f, 0.f};

  // A tile: 96 rows x 16 chunks = 1536 chunks; 256 thr -> 6 each. Same B.
#define STAGE(bi, kt)                                                          \
  {                                                                            \
    const int k0_ = (kt) * 128;                                                \
    _Pragma("unroll")                                                          \
    for (int i = 0; i < 6; ++i) {                                              \
      const int cd  = i * 256 + tid;                                           \
      const int row = cd >> 4;                                                 \
      const int cc  = (cd & 15) ^ (row & 7);                                   \
      async_copy16(A + (size_t)(m0 + row) * lda + k0_ + cc * 8,                \
                   (char*)&Alds[bi][0] + cd * 16);                             \
    }                                                                          \
    _Pragma("unroll")                                                          \
    for (int i = 0; i < 6; ++i) {                                              \
      const int cd  = i * 256 + tid;                                           \
      const int row = cd >> 4;                                                 \
      const int cc  = (cd & 15) ^ (row & 7);                                   \
      async_copy16(Bt + (size_t)(n0 + row) * ldb + k0_ + cc * 8,               \
                   (char*)&Blds[bi][0] + cd * 16);                             \
    }                                                                          \
  }

  STAGE(0, 0);
  __syncthreads();

  int cur = 0;
  for (int t = 0; t < ktiles; ++t) {
    if (t + 1 < ktiles) STAGE(cur ^ 1, t + 1);
    const int hi = lane >> 4;                  // 0..3
    #pragma unroll
    for (int kk = 0; kk < 4; ++kk) {
      bf16_8 af[3], bf[3];
      #pragma unroll
      for (int m = 0; m < 3; ++m) {
        const int ra = wrow * 48 + m * 16 + (lane & 15);
        const int ca = kk * 4 + hi;            // chunk col 0..15
        af[m] = *(const bf16_8*)((const char*)&Alds[cur][0] +
                                 (ra * 16 + (ca ^ (ra & 7))) * 16);
      }
      #pragma unroll
      for (int n = 0; n < 3; ++n) {
        const int rb = wcol * 48 + n * 16 + (lane & 15);
        const int cb = kk * 4 + hi;
        bf[n] = *(const bf16_8*)((const char*)&Blds[cur][0] +
                                 (rb * 16 + (cb ^ (rb & 7))) * 16);
      }
      #pragma unroll
      for (int m = 0; m < 3; ++m)
        #pragma unroll
        for (int n = 0; n < 3; ++n)
          acc[m][n] = __builtin_amdgcn_mfma_f32_16x16x32_bf16(af[m], bf[n],
                                                              acc[m][n], 0, 0, 0);
    }
    __syncthreads();
    cur ^= 1;
  }
#undef STAGE

  // D col = lane&15, row = 4*(lane>>4)+reg
  const int rbase = (lane >> 4) * 4;
  const int cf    = lane & 15;
  #pragma unroll
  for (int m = 0; m < 3; ++m) {
    #pragma unroll
    for (int n = 0; n < 3; ++n) {
      #pragma unroll
      for (int reg = 0; reg < 4; ++reg) {
        const int gr = m0 + wrow * 48 + m * 16 + rbase + reg;
        const int gc = n0 + wcol * 48 + n * 16 + cf;
        float v = fmaxf(acc[m][n][reg] * scales[gr] + bias[gc], 0.0f);
        H[(size_t)gr * HDIM + gc] = f2bf(v);
      }
    }
  }
}

// ---- GEMM2: BM=96, BN=32, BK=128, grid 32x8 = 256 blocks (R10-proven) ----
// 384 thr = 6 waves (6m x 1n); wave-tile 16x32 = acc[1][2]; 6 K-tiles.
// out[(row%3)*262144 + (row/3)*256 + col] = acc + bias[col]

__global__ __launch_bounds__(384)
void gemm2_fused(const ushort_t* __restrict__ A, int lda,
                 const ushort_t* __restrict__ Bt, int ldb,
                 int ktiles,
                 const float* __restrict__ bias,
                 float* __restrict__ outp) {
  __shared__ __align__(16) ushort_t Alds[2][96 * 128];   // 2 x 24 KB
  __shared__ __align__(16) ushort_t Blds[2][32 * 128];   // 2 x  8 KB
  const int tid  = threadIdx.x;
  const int lane = tid & 63;
  const int wv   = tid >> 6;      // 0..5 -> 16 rows each
  const int m0   = blockIdx.x * 96;
  const int n0   = blockIdx.y * 32;

  f32x4 acc[2];
  acc[0] = (f32x4){0.f, 0.f, 0.f, 0.f};
  acc[1] = (f32x4){0.f, 0.f, 0.f, 0.f};

#define STAGE(bi, kt)                                                          \
  {                                                                            \
    const int k0_ = (kt) * 128;                                                \
    _Pragma("unroll")                                                          \
    for (int i = 0; i < 4; ++i) {                                              \
      const int cd  = i * 384 + tid;                                           \
      const int row = cd >> 4;                                                 \
      const int cc  = (cd & 15) ^ (row & 7);                                   \
      async_copy16(A + (size_t)(m0 + row) * lda + k0_ + cc * 8,                \
                   (char*)&Alds[bi][0] + cd * 16);                             \
    }                                                                          \
    {                                                                          \
      const int cd  = tid;                                                     \
      const int row = cd >> 4;                                                 \
      const int cc  = (cd & 15) ^ (row & 7);                                   \
      async_copy16(Bt + (size_t)(n0 + row) * ldb + k0_ + cc * 8,               \
                   (char*)&Blds[bi][0] + cd * 16);                             \
    }                                                                          \
    if (tid < 128) {                                                           \
      const int cd  = 384 + tid;                                               \
      const int row = cd >> 4;                                                 \
      const int cc  = (cd & 15) ^ (row & 7);                                   \
      async_copy16(Bt + (size_t)(n0 + row) * ldb + k0_ + cc * 8,               \
                   (char*)&Blds[bi][0] + cd * 16);                             \
    }                                                                          \
  }

  STAGE(0, 0);
  __syncthreads();

  int cur = 0;
  for (int t = 0; t < ktiles; ++t) {
    if (t + 1 < ktiles) STAGE(cur ^ 1, t + 1);
    const int hi = lane >> 4;
    #pragma unroll
    for (int kk = 0; kk < 4; ++kk) {
      bf16_8 af, bf[2];
      {
        const int ra = wv * 16 + (lane & 15);
        const int ca = kk * 4 + hi;
        af = *(const bf16_8*)((const char*)&Alds[cur][0] +
                              (ra * 16 + (ca ^ (ra & 7))) * 16);
      }
      #pragma unroll
      for (int n = 0; n < 2; ++n) {
        const int rb = n * 16 + (lane & 15);
        const int cb = kk * 4 + hi;
        bf[n] = *(const bf16_8*)((const char*)&Blds[cur][0] +
                                 (rb * 16 + (cb ^ (rb & 7))) * 16);
      }
      #pragma unroll
      for (int n = 0; n < 2; ++n)
        acc[n] = __builtin_amdgcn_mfma_f32_16x16x32_bf16(af, bf[n], acc[n], 0, 0, 0);
    }
    __syncthreads();
    cur ^= 1;
  }
#undef STAGE

  const int rbase = (lane >> 4) * 4;
  const int cf    = lane & 15;
  #pragma unroll
  for (int n = 0; n < 2; ++n) {
    #pragma unroll
    for (int reg = 0; reg < 4; ++reg) {
      const int gr = m0 + wv * 16 + rbase + reg;
      const int gc = n0 + n * 16 + cf;
      float v = acc[n][reg] + bias[gc];
      outp[(size_t)(gr % 3) * (1024 * ODIM) + (size_t)(gr / 3) * ODIM + gc] = v;
    }
  }
}

// ---- launch --------------------------------------------------------------

extern "C" void kernel_launch(void* const* d_in, const int* in_sizes, int n_in,
                              void* d_out, int out_size, void* d_ws, size_t ws_size,
                              hipStream_t stream) {
  const int*   X  = (const int*)d_in[0];
  const float* W1 = (const float*)d_in[1];
  const float* b1 = (const float*)d_in[2];
  const float* W2 = (const float*)d_in[3];
  const float* b2 = (const float*)d_in[4];
  float* out = (float*)d_out;

  char* ws = (char*)d_ws;
  ushort_t* A      = (ushort_t*)(ws);                  // 3072*4224*2 = 25,952,256 B
  ushort_t* W1T    = (ushort_t*)(ws + 25952256);       //  768*4224*2 =  6,488,064 B
  ushort_t* H      = (ushort_t*)(ws + 32440320);       // 3072*768*2  =  4,718,592 B
  ushort_t* W2T    = (ushort_t*)(ws + 37158912);       //  256*768*2  =    393,216 B
  float*    scales = (float*)   (ws + 37552128);       //     12,288 B

  // prep: 3072 hist blocks + 792 W1-transpose tiles + 48 W2-transpose tiles
  prep_kernel<<<NROWS + 792 + 48, 256, 0, stream>>>(X, W1, W2, A, W1T, W2T, scales);

  // GEMM1: M=3072 N=768 K=4224 (33 tiles of 128); grid 32x8 = 256 blocks
  gemm1_fused<<<dim3(NROWS / 96, HDIM / 96), 256, 0, stream>>>(
      A, KPAD, W1T, KPAD, KPAD / 128, scales, b1, H);

  // GEMM2: M=3072 N=256 K=768 (6 tiles of 128); grid 32x8 = 256 blocks
  gemm2_fused<<<dim3(NROWS / 96, ODIM / 32), 384, 0, stream>>>(
      H, HDIM, W2T, HDIM, HDIM / 128, b2, out);
}